// Round 15
// baseline (611.672 us; speedup 1.0000x reference)
//
#include <hip/hip_runtime.h>
#include <hip/hip_bf16.h>

#define Bn 128
#define Tn 512
#define En 100
#define G4 256   // 4*HD
#define Hn 128
#define Kn 12

typedef short bf16x8 __attribute__((ext_vector_type(8)));
typedef float f32x4 __attribute__((ext_vector_type(4)));

__device__ __forceinline__ float exp2_hw(float x) {
  float r; asm("v_exp_f32 %0, %1" : "=v"(r) : "v"(x)); return r;
}
__device__ __forceinline__ float rcp_hw(float x) {
  float r; asm("v_rcp_f32 %0, %1" : "=v"(r) : "v"(x)); return r;
}
__device__ __forceinline__ float fast_sigm(float x) {
  return rcp_hw(1.0f + exp2_hw(x * -1.4426950408889634f));
}
__device__ __forceinline__ float fast_tanh(float x) {
  return 1.0f - 2.0f * rcp_hw(1.0f + exp2_hw(x * 2.8853900817779268f));
}
// pack 2 floats -> 2 bf16 (RNE) in one u32
__device__ __forceinline__ unsigned int pk2bf(float a, float b) {
  unsigned int ua = __float_as_uint(a); ua += 0x7FFFu + ((ua >> 16) & 1u);
  unsigned int ub = __float_as_uint(b); ub += 0x7FFFu + ((ub >> 16) & 1u);
  return (ua >> 16) | (ub & 0xFFFF0000u);
}

// ---------------- K1: proj via MFMA bf16 (validated r10) ------------------
__global__ __launch_bounds__(256) void proj_kernel(
    const int* __restrict__ sent, const float* __restrict__ embed,
    const float* __restrict__ WihF, const float* __restrict__ WihB,
    const float* __restrict__ bihF, const float* __restrict__ bhhF,
    const float* __restrict__ bihB, const float* __restrict__ bhhB,
    float* __restrict__ xgF, float* __restrict__ xgB, int dirSel) {
  __shared__ __align__(16) unsigned short embS[64][128];
  __shared__ __align__(16) unsigned short wS[128][128];
  __shared__ float bias_s[128];
  const int tid = threadIdx.x;
  const int nhalf = blockIdx.y;
  const int dir = (dirSel >= 0) ? dirSel : (int)blockIdx.z;
  const float* Wih = dir ? WihB : WihF;
  const float* bih = dir ? bihB : bihF;
  const float* bhh = dir ? bhhB : bhhF;
  float* xg = dir ? xgB : xgF;
  const int n0 = blockIdx.x * 64;
  const int g0 = nhalf * 128;
  {
    const int t = tid >> 2, q = tid & 3;
    const int row = sent[n0 + t];
    const float* er = embed + (size_t)row * En;
    for (int c = q; c < 16; c += 4) {
      uint4 wv;
      if (c < 12) {
        const float4 f0 = *(const float4*)(er + 8 * c);
        const float4 f1 = *(const float4*)(er + 8 * c + 4);
        wv = make_uint4(pk2bf(f0.x, f0.y), pk2bf(f0.z, f0.w),
                        pk2bf(f1.x, f1.y), pk2bf(f1.z, f1.w));
      } else if (c == 12) {
        float f[8];
#pragma unroll
        for (int j = 0; j < 8; ++j) { const int e = 96 + j; f[j] = (e < En) ? er[e] : 0.f; }
        wv = make_uint4(pk2bf(f[0], f[1]), pk2bf(f[2], f[3]),
                        pk2bf(f[4], f[5]), pk2bf(f[6], f[7]));
      } else {
        wv = make_uint4(0, 0, 0, 0);
      }
      *(uint4*)&embS[t][8 * (c ^ (t & 7))] = wv;
    }
  }
  {
    const int r = tid >> 1, q = tid & 1;
    const float* wr = Wih + (size_t)(g0 + r) * En;
    for (int c = q; c < 16; c += 2) {
      uint4 wv;
      if (c < 12) {
        const float4 f0 = *(const float4*)(wr + 8 * c);
        const float4 f1 = *(const float4*)(wr + 8 * c + 4);
        wv = make_uint4(pk2bf(f0.x, f0.y), pk2bf(f0.z, f0.w),
                        pk2bf(f1.x, f1.y), pk2bf(f1.z, f1.w));
      } else if (c == 12) {
        float f[8];
#pragma unroll
        for (int j = 0; j < 8; ++j) { const int e = 96 + j; f[j] = (e < En) ? wr[e] : 0.f; }
        wv = make_uint4(pk2bf(f[0], f[1]), pk2bf(f[2], f[3]),
                        pk2bf(f[4], f[5]), pk2bf(f[6], f[7]));
      } else {
        wv = make_uint4(0, 0, 0, 0);
      }
      *(uint4*)&wS[r][8 * (c ^ (r & 7))] = wv;
    }
  }
  if (tid < 128) bias_s[tid] = bih[g0 + tid] + bhh[g0 + tid];
  __syncthreads();
  const int m = tid >> 6;
  const int lane = tid & 63;
  const int lr = lane & 15;
  const int lq = lane >> 4;
  const int t = 16 * m + lr;
  f32x4 acc[8] = {};
#pragma unroll
  for (int ks = 0; ks < 4; ++ks) {
    const int cs = 4 * ks + lq;
    const bf16x8 af = *(const bf16x8*)&embS[t][8 * (cs ^ (lr & 7))];
#pragma unroll
    for (int nt = 0; nt < 8; ++nt) {
      const int g = 16 * nt + lr;
      const bf16x8 bf = *(const bf16x8*)&wS[g][8 * (cs ^ (lr & 7))];
      acc[nt] = __builtin_amdgcn_mfma_f32_16x16x32_bf16(af, bf, acc[nt], 0, 0, 0);
    }
  }
  float* xbase = xg + (size_t)(n0 + 16 * m) * G4 + g0;
#pragma unroll
  for (int nt = 0; nt < 8; ++nt) {
    const int g = 16 * nt + lr;
    const float bv = bias_s[g];
#pragma unroll
    for (int j = 0; j < 4; ++j) {
      const int tok = 4 * lq + j;
      xbase[(size_t)tok * G4 + g] = acc[nt][j] + bv;
    }
  }
}

// ---------------- K2: LSTM recurrence, single-wave MFMA GEMV --------------
// One wave per (dir,b). Per step: h[1x64] @ W[64x256] as 32 MFMA 16x16x32
// with h replicated across all 16 A-rows (D rows identical). B-fragments
// (W, K-permuted) are PINNED IN AGPRs via tie-constraint asm and read
// DIRECTLY by the MFMA "a" operand (ISA: A/B may be AGPR) — zero per-step
// weight access, immune to the allocator (defeats r3/r4/r5/r14 failures).
// K-permutation pi(32c+8q'+j)=16*(2c+(j>>2))+4q'+(j&3) applied to BOTH h
// and W makes the A-frag buildable from the lane-local C-layout h values
// with 16 shfls + 8 packs. xg preloads into acc[nt][0] as the MFMA C
// operand (regs 1-3 carry never-read finite garbage). No LDS, no barrier.
__global__ __launch_bounds__(64, 1) void lstm_kernel(
    const float* __restrict__ xgF, const float* __restrict__ xgB,
    const float* __restrict__ WhhF, const float* __restrict__ WhhB,
    const float* __restrict__ h0, const float* __restrict__ c0,
    float* __restrict__ feats, int dirSel) {
  int d, b;
  if (dirSel < 0) { d = blockIdx.x >> 7; b = blockIdx.x & 127; }
  else            { d = dirSel;          b = blockIdx.x; }
  const int lane = threadIdx.x & 63;
  const int cl = lane & 15;
  const int lq = lane >> 4;
  const float* xg = d ? xgB : xgF;
  const float* Whh = d ? WhhB : WhhF;
  // --- stage B-frags (K-permuted, bf16) and pin in AGPRs ---
  bf16x8 bfr[16][2];
#pragma unroll
  for (int nt = 0; nt < 16; ++nt) {
#pragma unroll
    for (int c = 0; c < 2; ++c) {
      const float* wr = Whh + (size_t)(16 * nt + cl) * 64;
      float e0 = wr[16 * (2 * c + 0) + 4 * lq + 0];
      float e1 = wr[16 * (2 * c + 0) + 4 * lq + 1];
      float e2 = wr[16 * (2 * c + 0) + 4 * lq + 2];
      float e3 = wr[16 * (2 * c + 0) + 4 * lq + 3];
      float e4 = wr[16 * (2 * c + 1) + 4 * lq + 0];
      float e5 = wr[16 * (2 * c + 1) + 4 * lq + 1];
      float e6 = wr[16 * (2 * c + 1) + 4 * lq + 2];
      float e7 = wr[16 * (2 * c + 1) + 4 * lq + 3];
      const uint4 pk = make_uint4(pk2bf(e0, e1), pk2bf(e2, e3),
                                  pk2bf(e4, e5), pk2bf(e6, e7));
      const bf16x8 v = __builtin_bit_cast(bf16x8, pk);
      asm volatile("" : "=a"(bfr[nt][c]) : "0"(v));  // pin to AGPR, opaque
    }
  }
  // --- state: lane owns h,c of units 16q + cl (replicated across lq) ---
  float hq[4], cq[4];
#pragma unroll
  for (int q = 0; q < 4; ++q) {
    hq[q] = h0[(size_t)d * (Bn * 64) + (size_t)b * 64 + 16 * q + cl];
    cq[q] = c0[(size_t)d * (Bn * 64) + (size_t)b * 64 + 16 * q + cl];
  }
  f32x4 acc[16];
#pragma unroll
  for (int nt = 0; nt < 16; ++nt) acc[nt] = (f32x4){0.f, 0.f, 0.f, 0.f};
  const float* xbase = xg + (size_t)b * Tn * G4 + cl;
  float* fb = feats + (size_t)b * Tn * Hn + d * 64 + cl;
  const int t0 = d ? (Tn - 1) : 0;
  const int ts = d ? -1 : 1;
  float pA[16], pB[16];
#pragma unroll
  for (int nt = 0; nt < 16; ++nt) {
    pA[nt] = xbase[(size_t)t0 * G4 + 16 * nt];
    pB[nt] = xbase[(size_t)(t0 + ts) * G4 + 16 * nt];
  }

#define STEP(P, T, PF, TN) do {                                                \
    float s_[16];                                                              \
    _Pragma("unroll")                                                          \
    for (int j = 0; j < 8; ++j) {                                              \
      s_[j]     = __shfl(hq[(j >> 2)],     4 * lq + (j & 3));                  \
      s_[8 + j] = __shfl(hq[2 + (j >> 2)], 4 * lq + (j & 3));                  \
    }                                                                          \
    const bf16x8 a0_ = __builtin_bit_cast(bf16x8, make_uint4(                  \
        pk2bf(s_[0], s_[1]), pk2bf(s_[2], s_[3]),                              \
        pk2bf(s_[4], s_[5]), pk2bf(s_[6], s_[7])));                            \
    const bf16x8 a1_ = __builtin_bit_cast(bf16x8, make_uint4(                  \
        pk2bf(s_[8], s_[9]), pk2bf(s_[10], s_[11]),                            \
        pk2bf(s_[12], s_[13]), pk2bf(s_[14], s_[15])));                        \
    _Pragma("unroll")                                                          \
    for (int nt = 0; nt < 16; ++nt) acc[nt][0] = P[nt];                        \
    if (PF) {                                                                  \
      _Pragma("unroll")                                                        \
      for (int nt = 0; nt < 16; ++nt)                                          \
        P[nt] = xbase[(size_t)(TN) * G4 + 16 * nt];                            \
    }                                                                          \
    _Pragma("unroll")                                                          \
    for (int nt = 0; nt < 16; ++nt) {                                          \
      asm volatile("v_mfma_f32_16x16x32_bf16 %0, %1, %2, %0"                   \
                   : "+v"(acc[nt]) : "v"(a0_), "a"(bfr[nt][0]));               \
      asm volatile("v_mfma_f32_16x16x32_bf16 %0, %1, %2, %0"                   \
                   : "+v"(acc[nt]) : "v"(a1_), "a"(bfr[nt][1]));               \
    }                                                                          \
    asm volatile("s_nop 7\n\ts_nop 7\n\ts_nop 7"                               \
                 : "+v"(acc[12]), "+v"(acc[13]), "+v"(acc[14]), "+v"(acc[15]));\
    _Pragma("unroll")                                                          \
    for (int q = 0; q < 4; ++q) {                                              \
      const float ii = fast_sigm(acc[q][0]);                                   \
      const float ff = fast_sigm(acc[4 + q][0]);                               \
      const float gg = fast_tanh(acc[8 + q][0]);                               \
      const float oo = fast_sigm(acc[12 + q][0]);                              \
      cq[q] = fmaf(ff, cq[q], ii * gg);                                        \
      hq[q] = oo * fast_tanh(cq[q]);                                           \
    }                                                                          \
    if (lane < 16) {                                                           \
      _Pragma("unroll")                                                        \
      for (int q = 0; q < 4; ++q) fb[(size_t)(T) * Hn + 16 * q] = hq[q];       \
    }                                                                          \
  } while (0)

  for (int s = 0; s < Tn; s += 2) {
    const int tA = t0 + s * ts;
    const int tB = tA + ts;
    STEP(pA, tA, (s + 2 < Tn), tA + 2 * ts);
    STEP(pB, tB, (s + 3 < Tn), tB + 2 * ts);
  }
#undef STEP
}

// ---------------- K3: emissions = feats @ W_out^T + b_out ----------------
__global__ __launch_bounds__(256) void emis_kernel(
    const float* __restrict__ feats, const float* __restrict__ Wout,
    const float* __restrict__ bout, float* __restrict__ em) {
  __shared__ __align__(16) float Wo[Kn * Hn];
  __shared__ float bo[Kn];
  const int tid = threadIdx.x;
  for (int i = tid; i < Kn * Hn; i += 256) Wo[i] = Wout[i];
  if (tid < Kn) bo[tid] = bout[tid];
  __syncthreads();
  const int n = blockIdx.x * 256 + tid;
  float acc[Kn];
#pragma unroll
  for (int k = 0; k < Kn; ++k) acc[k] = bo[k];
  const float4* fp = (const float4*)(feats + (size_t)n * Hn);
#pragma unroll 4
  for (int d4 = 0; d4 < 32; ++d4) {
    const float4 v = fp[d4];
#pragma unroll
    for (int k = 0; k < Kn; ++k) {
      const float4 w = *(const float4*)&Wo[k * Hn + d4 * 4];
      acc[k] = fmaf(v.x, w.x, acc[k]);
      acc[k] = fmaf(v.y, w.y, acc[k]);
      acc[k] = fmaf(v.z, w.z, acc[k]);
      acc[k] = fmaf(v.w, w.w, acc[k]);
    }
  }
  float* ep = em + (size_t)n * Kn;
#pragma unroll
  for (int k = 0; k < Kn; k += 4)
    *(float4*)&ep[k] = make_float4(acc[k], acc[k + 1], acc[k + 2], acc[k + 3]);
}

// ---------------- K4: Viterbi (one wave per sentence) ----------------
#define AMAX(v, a, v2, a2) { if ((v2) > (v)) { (v) = (v2); (a) = (a2); } }

__global__ __launch_bounds__(64) void viterbi_kernel(
    const float* __restrict__ em, const float* __restrict__ trans,
    float* __restrict__ out) {
  __shared__ __align__(16) float em_s[Tn * Kn];
  __shared__ float trans_s[Kn * Kn];
  __shared__ unsigned char bp[(Tn - 1) * Kn];
  __shared__ short path_s[Tn];
  const int tid = threadIdx.x;
  const int b = blockIdx.x;
  {
    const float4* ebv = (const float4*)(em + (size_t)b * Tn * Kn);
    float4* emv = (float4*)em_s;
    for (int i = tid; i < (Tn * Kn) / 4; i += 64) emv[i] = ebv[i];
  }
  for (int i = tid; i < Kn * Kn; i += 64) trans_s[i] = trans[i];
  __syncthreads();
  const int lane = (tid < Kn) ? tid : 0;
  float treg[Kn];
#pragma unroll
  for (int f = 0; f < Kn; ++f) treg[f] = trans_s[f * Kn + lane];
  float prev = em_s[lane];
  for (int t = 1; t < Tn; ++t) {
    float cv[Kn];
#pragma unroll
    for (int f = 0; f < Kn; ++f) cv[f] = __shfl(prev, f) + treg[f];
    float m0 = cv[0], m1 = cv[2], m2 = cv[4], m3 = cv[6], m4 = cv[8], m5 = cv[10];
    int a0 = 0, a1 = 2, a2 = 4, a3 = 6, a4 = 8, a5 = 10;
    AMAX(m0, a0, cv[1], 1);  AMAX(m1, a1, cv[3], 3);
    AMAX(m2, a2, cv[5], 5);  AMAX(m3, a3, cv[7], 7);
    AMAX(m4, a4, cv[9], 9);  AMAX(m5, a5, cv[11], 11);
    AMAX(m0, a0, m1, a1); AMAX(m2, a2, m3, a3); AMAX(m4, a4, m5, a5);
    AMAX(m0, a0, m2, a2); AMAX(m0, a0, m4, a4);
    prev = em_s[t * Kn + lane] + m0;
    if (tid < Kn) bp[(t - 1) * Kn + tid] = (unsigned char)a0;
  }
  float fv[Kn];
#pragma unroll
  for (int f = 0; f < Kn; ++f) fv[f] = __shfl(prev, f);
  float m0 = fv[0], m1 = fv[2], m2 = fv[4], m3 = fv[6], m4 = fv[8], m5 = fv[10];
  int a0 = 0, a1 = 2, a2 = 4, a3 = 6, a4 = 8, a5 = 10;
  AMAX(m0, a0, fv[1], 1);  AMAX(m1, a1, fv[3], 3);
  AMAX(m2, a2, fv[5], 5);  AMAX(m3, a3, fv[7], 7);
  AMAX(m4, a4, fv[9], 9);  AMAX(m5, a5, fv[11], 11);
  AMAX(m0, a0, m1, a1); AMAX(m2, a2, m3, a3); AMAX(m4, a4, m5, a5);
  AMAX(m0, a0, m2, a2); AMAX(m0, a0, m4, a4);
  __syncthreads();
  if (tid == 0) {
    out[b] = m0;
    int cur = a0;
    for (int i = Tn - 2; i >= 0; --i) {
      path_s[i + 1] = (short)cur;
      cur = bp[i * Kn + cur];
    }
    path_s[0] = (short)cur;
  }
  __syncthreads();
  for (int i = tid; i < Tn; i += 64)
    out[Bn + (size_t)b * Tn + i] = (float)path_s[i];
}

extern "C" void kernel_launch(void* const* d_in, const int* in_sizes, int n_in,
                              void* d_out, int out_size, void* d_ws, size_t ws_size,
                              hipStream_t stream) {
  const int*   sent  = (const int*)d_in[0];
  const float* embed = (const float*)d_in[1];
  const float* Wih_f = (const float*)d_in[2];
  const float* Whh_f = (const float*)d_in[3];
  const float* bih_f = (const float*)d_in[4];
  const float* bhh_f = (const float*)d_in[5];
  const float* Wih_b = (const float*)d_in[6];
  const float* Whh_b = (const float*)d_in[7];
  const float* bih_b = (const float*)d_in[8];
  const float* bhh_b = (const float*)d_in[9];
  const float* Wout  = (const float*)d_in[10];
  const float* bout  = (const float*)d_in[11];
  const float* trans = (const float*)d_in[12];
  const float* h0    = (const float*)d_in[13];
  const float* c0    = (const float*)d_in[14];
  float* out = (float*)d_out;

  char* ws = (char*)d_ws;
  const size_t xgBytes   = (size_t)Bn * Tn * G4 * sizeof(float);  // 64 MiB
  const size_t featBytes = (size_t)Bn * Tn * Hn * sizeof(float);  // 32 MiB
  const size_t emBytes   = (size_t)Bn * Tn * Kn * sizeof(float);  //  3 MiB
  const int tokBlocks = (Bn * Tn) / 64;  // 1024

  if (ws_size >= 2 * xgBytes + featBytes + emBytes) {
    float* xgF   = (float*)ws;
    float* xgB   = (float*)(ws + xgBytes);
    float* feats = (float*)(ws + 2 * xgBytes);
    float* emis  = (float*)(ws + 2 * xgBytes + featBytes);
    proj_kernel<<<dim3(tokBlocks, 2, 2), 256, 0, stream>>>(
        sent, embed, Wih_f, Wih_b, bih_f, bhh_f, bih_b, bhh_b, xgF, xgB, -1);
    lstm_kernel<<<256, 64, 0, stream>>>(xgF, xgB, Whh_f, Whh_b, h0, c0, feats, -1);
    emis_kernel<<<256, 256, 0, stream>>>(feats, Wout, bout, emis);
    viterbi_kernel<<<128, 64, 0, stream>>>(emis, trans, out);
  } else {
    float* xgS   = (float*)ws;
    float* feats = (float*)(ws + xgBytes);
    float* emis  = (float*)(ws + xgBytes + featBytes);
    proj_kernel<<<dim3(tokBlocks, 2, 1), 256, 0, stream>>>(
        sent, embed, Wih_f, Wih_b, bih_f, bhh_f, bih_b, bhh_b, xgS, xgS, 0);
    lstm_kernel<<<128, 64, 0, stream>>>(xgS, xgS, Whh_f, Whh_f, h0, c0, feats, 0);
    proj_kernel<<<dim3(tokBlocks, 2, 1), 256, 0, stream>>>(
        sent, embed, Wih_f, Wih_b, bih_f, bhh_f, bih_b, bhh_b, xgS, xgS, 1);
    lstm_kernel<<<128, 64, 0, stream>>>(xgS, xgS, Whh_b, Whh_b, h0, c0, feats, 1);
    emis_kernel<<<256, 256, 0, stream>>>(feats, Wout, bout, emis);
    viterbi_kernel<<<128, 64, 0, stream>>>(emis, trans, out);
  }
}

// Round 16
// 406.779 us; speedup vs baseline: 1.5037x; 1.5037x over previous
//
#include <hip/hip_runtime.h>
#include <hip/hip_bf16.h>

#define Bn 128
#define Tn 512
#define En 100
#define G4 256   // 4*HD
#define Hn 128
#define Kn 12

typedef short bf16x8 __attribute__((ext_vector_type(8)));
typedef float f32x4 __attribute__((ext_vector_type(4)));

// Raw barrier: lgkmcnt(0) + s_barrier, no vmcnt drain (prefetch survives).
__device__ __forceinline__ void wg_barrier() {
  asm volatile("s_waitcnt lgkmcnt(0)" ::: "memory");
  __builtin_amdgcn_s_barrier();
  asm volatile("" ::: "memory");
}

__device__ __forceinline__ float exp2_hw(float x) {
  float r; asm("v_exp_f32 %0, %1" : "=v"(r) : "v"(x)); return r;
}
__device__ __forceinline__ float rcp_hw(float x) {
  float r; asm("v_rcp_f32 %0, %1" : "=v"(r) : "v"(x)); return r;
}
__device__ __forceinline__ float fast_tanh(float x) {
  return 1.0f - 2.0f * rcp_hw(1.0f + exp2_hw(x * 2.8853900817779268f));
}
// pack 2 floats -> 2 bf16 (RNE) in one u32
__device__ __forceinline__ unsigned int pk2bf(float a, float b) {
  unsigned int ua = __float_as_uint(a); ua += 0x7FFFu + ((ua >> 16) & 1u);
  unsigned int ub = __float_as_uint(b); ub += 0x7FFFu + ((ub >> 16) & 1u);
  return (ua >> 16) | (ub & 0xFFFF0000u);
}

// ---------------- K1: proj via MFMA bf16 (validated r10) ------------------
__global__ __launch_bounds__(256) void proj_kernel(
    const int* __restrict__ sent, const float* __restrict__ embed,
    const float* __restrict__ WihF, const float* __restrict__ WihB,
    const float* __restrict__ bihF, const float* __restrict__ bhhF,
    const float* __restrict__ bihB, const float* __restrict__ bhhB,
    float* __restrict__ xgF, float* __restrict__ xgB, int dirSel) {
  __shared__ __align__(16) unsigned short embS[64][128];
  __shared__ __align__(16) unsigned short wS[128][128];
  __shared__ float bias_s[128];
  const int tid = threadIdx.x;
  const int nhalf = blockIdx.y;
  const int dir = (dirSel >= 0) ? dirSel : (int)blockIdx.z;
  const float* Wih = dir ? WihB : WihF;
  const float* bih = dir ? bihB : bihF;
  const float* bhh = dir ? bhhB : bhhF;
  float* xg = dir ? xgB : xgF;
  const int n0 = blockIdx.x * 64;
  const int g0 = nhalf * 128;
  {
    const int t = tid >> 2, q = tid & 3;
    const int row = sent[n0 + t];
    const float* er = embed + (size_t)row * En;
    for (int c = q; c < 16; c += 4) {
      uint4 wv;
      if (c < 12) {
        const float4 f0 = *(const float4*)(er + 8 * c);
        const float4 f1 = *(const float4*)(er + 8 * c + 4);
        wv = make_uint4(pk2bf(f0.x, f0.y), pk2bf(f0.z, f0.w),
                        pk2bf(f1.x, f1.y), pk2bf(f1.z, f1.w));
      } else if (c == 12) {
        float f[8];
#pragma unroll
        for (int j = 0; j < 8; ++j) { const int e = 96 + j; f[j] = (e < En) ? er[e] : 0.f; }
        wv = make_uint4(pk2bf(f[0], f[1]), pk2bf(f[2], f[3]),
                        pk2bf(f[4], f[5]), pk2bf(f[6], f[7]));
      } else {
        wv = make_uint4(0, 0, 0, 0);
      }
      *(uint4*)&embS[t][8 * (c ^ (t & 7))] = wv;
    }
  }
  {
    const int r = tid >> 1, q = tid & 1;
    const float* wr = Wih + (size_t)(g0 + r) * En;
    for (int c = q; c < 16; c += 2) {
      uint4 wv;
      if (c < 12) {
        const float4 f0 = *(const float4*)(wr + 8 * c);
        const float4 f1 = *(const float4*)(wr + 8 * c + 4);
        wv = make_uint4(pk2bf(f0.x, f0.y), pk2bf(f0.z, f0.w),
                        pk2bf(f1.x, f1.y), pk2bf(f1.z, f1.w));
      } else if (c == 12) {
        float f[8];
#pragma unroll
        for (int j = 0; j < 8; ++j) { const int e = 96 + j; f[j] = (e < En) ? wr[e] : 0.f; }
        wv = make_uint4(pk2bf(f[0], f[1]), pk2bf(f[2], f[3]),
                        pk2bf(f[4], f[5]), pk2bf(f[6], f[7]));
      } else {
        wv = make_uint4(0, 0, 0, 0);
      }
      *(uint4*)&wS[r][8 * (c ^ (r & 7))] = wv;
    }
  }
  if (tid < 128) bias_s[tid] = bih[g0 + tid] + bhh[g0 + tid];
  __syncthreads();
  const int m = tid >> 6;
  const int lane = tid & 63;
  const int lr = lane & 15;
  const int lq = lane >> 4;
  const int t = 16 * m + lr;
  f32x4 acc[8] = {};
#pragma unroll
  for (int ks = 0; ks < 4; ++ks) {
    const int cs = 4 * ks + lq;
    const bf16x8 af = *(const bf16x8*)&embS[t][8 * (cs ^ (lr & 7))];
#pragma unroll
    for (int nt = 0; nt < 8; ++nt) {
      const int g = 16 * nt + lr;
      const bf16x8 bf = *(const bf16x8*)&wS[g][8 * (cs ^ (lr & 7))];
      acc[nt] = __builtin_amdgcn_mfma_f32_16x16x32_bf16(af, bf, acc[nt], 0, 0, 0);
    }
  }
  float* xbase = xg + (size_t)(n0 + 16 * m) * G4 + g0;
#pragma unroll
  for (int nt = 0; nt < 8; ++nt) {
    const int g = 16 * nt + lr;
    const float bv = bias_s[g];
#pragma unroll
    for (int j = 0; j < 4; ++j) {
      const int tok = 4 * lq + j;
      xbase[(size_t)tok * G4 + g] = acc[nt][j] + bv;
    }
  }
}

// ---------------- K2: LSTM recurrence (r8/r10 best: 245 us) ---------------
__global__ __launch_bounds__(512, 2) void lstm_kernel(
    const float* __restrict__ xgF, const float* __restrict__ xgB,
    const float* __restrict__ WhhF, const float* __restrict__ WhhB,
    const float* __restrict__ h0, const float* __restrict__ c0,
    float* __restrict__ feats, int dirSel) {
  __shared__ __align__(16) float h_s[2][64];
  int d, b;
  if (dirSel < 0) { d = blockIdx.x >> 7; b = blockIdx.x & 127; }
  else            { d = dirSel;          b = blockIdx.x; }
  const int tid = threadIdx.x;
  const int lane = tid & 63;
  const int w = tid >> 6;
  const int kh = lane >> 5;
  const int gt = (lane >> 3) & 3;
  const int u = lane & 7;
  const int unit = 8 * w + u;
  const int row = gt * 64 + unit;
  const float* xg = d ? xgB : xgF;
  const float* Whh = d ? WhhB : WhhF;
  float a00,a01,a02,a03,a04,a05,a06,a07,a08,a09,a10,a11,a12,a13,a14,a15,
        a16,a17,a18,a19,a20,a21,a22,a23,a24,a25,a26,a27,a28,a29,a30,a31;
  {
    const float4* wp = (const float4*)(Whh + (size_t)row * 64 + 32 * kh);
    const float4 w0 = wp[0], w1 = wp[1], w2 = wp[2], w3 = wp[3];
    const float4 w4 = wp[4], w5 = wp[5], w6 = wp[6], w7 = wp[7];
#define ST(A, V) asm volatile("v_accvgpr_write_b32 %0, %1" : "=a"(A) : "v"(V))
    ST(a00, w0.x); ST(a01, w0.y); ST(a02, w0.z); ST(a03, w0.w);
    ST(a04, w1.x); ST(a05, w1.y); ST(a06, w1.z); ST(a07, w1.w);
    ST(a08, w2.x); ST(a09, w2.y); ST(a10, w2.z); ST(a11, w2.w);
    ST(a12, w3.x); ST(a13, w3.y); ST(a14, w3.z); ST(a15, w3.w);
    ST(a16, w4.x); ST(a17, w4.y); ST(a18, w4.z); ST(a19, w4.w);
    ST(a20, w5.x); ST(a21, w5.y); ST(a22, w5.z); ST(a23, w5.w);
    ST(a24, w6.x); ST(a25, w6.y); ST(a26, w6.z); ST(a27, w6.w);
    ST(a28, w7.x); ST(a29, w7.y); ST(a30, w7.z); ST(a31, w7.w);
#undef ST
  }
  const bool isT = (gt == 2);
  const float fA = isT ? 1.0f : 0.0f;
  const float fB = isT ? -2.0f : 1.0f;
  const float fC = isT ? 2.8853900817779268f : -1.4426950408889634f;
  float c = 0.f;
  if (lane < 8) {
    c = c0[(size_t)d * (Bn * 64) + (size_t)b * 64 + unit];
    h_s[0][unit] = h0[(size_t)d * (Bn * 64) + (size_t)b * 64 + unit];
  }
  const float* xb = xg + (size_t)b * Tn * G4 + row;
  float* fbase = feats + (size_t)b * Tn * Hn + d * 64 + unit;
  const int t0 = d ? (Tn - 1) : 0;
  const int ts = d ? -1 : 1;
  float p0 = 0.f, p1 = 0.f, p2 = 0.f, p3 = 0.f;
  if (kh == 0) {
    p0 = xb[(size_t)t0 * G4];
    p1 = xb[(size_t)(t0 + ts) * G4];
    p2 = xb[(size_t)(t0 + 2 * ts) * G4];
    p3 = xb[(size_t)(t0 + 3 * ts) * G4];
  }

#define ARD8(U0,U1,U2,U3,U4,U5,U6,U7, A0,A1,A2,A3,A4,A5,A6,A7)                \
  asm volatile("v_accvgpr_read_b32 %0, %8\n\t"                                \
               "v_accvgpr_read_b32 %1, %9\n\t"                                \
               "v_accvgpr_read_b32 %2, %10\n\t"                               \
               "v_accvgpr_read_b32 %3, %11\n\t"                               \
               "v_accvgpr_read_b32 %4, %12\n\t"                               \
               "v_accvgpr_read_b32 %5, %13\n\t"                               \
               "v_accvgpr_read_b32 %6, %14\n\t"                               \
               "v_accvgpr_read_b32 %7, %15"                                   \
               : "=&v"(U0),"=&v"(U1),"=&v"(U2),"=&v"(U3),                     \
                 "=&v"(U4),"=&v"(U5),"=&v"(U6),"=&v"(U7)                      \
               : "a"(A0),"a"(A1),"a"(A2),"a"(A3),                             \
                 "a"(A4),"a"(A5),"a"(A6),"a"(A7))
#define F4(HV, U0, U1, U2, U3)                                                 \
    s0 = fmaf((HV).x, U0, s0); s1 = fmaf((HV).y, U1, s1);                      \
    s2 = fmaf((HV).z, U2, s2); s3 = fmaf((HV).w, U3, s3);

#define LSTM_STEP(P, TT, RB) do {                                              \
    wg_barrier();                                                              \
    const float4* hp = (const float4*)(&h_s[RB][32 * kh]);                     \
    const float4 h0v = hp[0], h1v = hp[1], h2v = hp[2], h3v = hp[3];           \
    const float4 h4v = hp[4], h5v = hp[5], h6v = hp[6], h7v = hp[7];           \
    float u00,u01,u02,u03,u04,u05,u06,u07,u08,u09,u10,u11,u12,u13,u14,u15,     \
          u16,u17,u18,u19,u20,u21,u22,u23,u24,u25,u26,u27,u28,u29,u30,u31;     \
    ARD8(u00,u01,u02,u03,u04,u05,u06,u07, a00,a01,a02,a03,a04,a05,a06,a07);    \
    ARD8(u08,u09,u10,u11,u12,u13,u14,u15, a08,a09,a10,a11,a12,a13,a14,a15);    \
    ARD8(u16,u17,u18,u19,u20,u21,u22,u23, a16,a17,a18,a19,a20,a21,a22,a23);    \
    ARD8(u24,u25,u26,u27,u28,u29,u30,u31, a24,a25,a26,a27,a28,a29,a30,a31);    \
    float s0 = 0.f, s1 = 0.f, s2 = 0.f, s3 = 0.f;                              \
    F4(h0v, u00,u01,u02,u03)                                                   \
    F4(h1v, u04,u05,u06,u07)                                                   \
    F4(h2v, u08,u09,u10,u11)                                                   \
    F4(h3v, u12,u13,u14,u15)                                                   \
    F4(h4v, u16,u17,u18,u19)                                                   \
    F4(h5v, u20,u21,u22,u23)                                                   \
    F4(h6v, u24,u25,u26,u27)                                                   \
    F4(h7v, u28,u29,u30,u31)                                                   \
    const float smine = (s0 + s1) + (s2 + s3);                                 \
    const float stot = smine + __shfl_xor(smine, 32);                          \
    const float accv = (P) + stot;                                             \
    const float act = fmaf(fB, rcp_hw(1.0f + exp2_hw(fC * accv)), fA);         \
    const float gF = __shfl_xor(act, 8);                                       \
    const float gG = __shfl_xor(act, 16);                                      \
    const float gO = __shfl_xor(act, 24);                                      \
    if (lane < 8) {                                                            \
      c = fmaf(gF, c, act * gG);                                               \
      const float hh = gO * fast_tanh(c);                                      \
      h_s[RB ^ 1][unit] = hh;                                                  \
      fbase[(size_t)(TT) * Hn] = hh;                                           \
    }                                                                          \
  } while (0)

  for (int s = 0; s < Tn; s += 4) {
    const int tA = t0 + s * ts;
    LSTM_STEP(p0, tA, 0);
    if (kh == 0 && s + 4 < Tn) p0 = xb[(size_t)(t0 + (s + 4) * ts) * G4];
    LSTM_STEP(p1, tA + ts, 1);
    if (kh == 0 && s + 5 < Tn) p1 = xb[(size_t)(t0 + (s + 5) * ts) * G4];
    LSTM_STEP(p2, tA + 2 * ts, 0);
    if (kh == 0 && s + 6 < Tn) p2 = xb[(size_t)(t0 + (s + 6) * ts) * G4];
    LSTM_STEP(p3, tA + 3 * ts, 1);
    if (kh == 0 && s + 7 < Tn) p3 = xb[(size_t)(t0 + (s + 7) * ts) * G4];
  }
#undef LSTM_STEP
#undef F4
#undef ARD8
}

// ---------------- K3: emissions, 4-lane cooperative ----------------------
// 4 lanes per token: group reads 64B contiguous (16 lines/instr vs 64),
// shfl_xor(1,2) reduce, 3 outputs/lane.
__global__ __launch_bounds__(256) void emis_kernel(
    const float* __restrict__ feats, const float* __restrict__ Wout,
    const float* __restrict__ bout, float* __restrict__ em) {
  __shared__ __align__(16) float Wo[Kn * Hn];
  __shared__ float bo[Kn];
  const int tid = threadIdx.x;
  for (int i = tid; i < Kn * Hn; i += 256) Wo[i] = Wout[i];
  if (tid < Kn) bo[tid] = bout[tid];
  __syncthreads();
  const int q = tid & 3;                       // lane within token group
  const int n = blockIdx.x * 64 + (tid >> 2);  // token
  float acc[Kn];
#pragma unroll
  for (int k = 0; k < Kn; ++k) acc[k] = 0.f;
  const float4* fp = (const float4*)(feats + (size_t)n * Hn);
#pragma unroll
  for (int c = 0; c < 8; ++c) {
    const float4 v = fp[q + 4 * c];            // 4 lanes cover 64B contiguous
#pragma unroll
    for (int k = 0; k < Kn; ++k) {
      const float4 w = *(const float4*)&Wo[k * Hn + (q + 4 * c) * 4];
      acc[k] = fmaf(v.x, w.x, acc[k]);
      acc[k] = fmaf(v.y, w.y, acc[k]);
      acc[k] = fmaf(v.z, w.z, acc[k]);
      acc[k] = fmaf(v.w, w.w, acc[k]);
    }
  }
#pragma unroll
  for (int k = 0; k < Kn; ++k) {
    acc[k] += __shfl_xor(acc[k], 1);
    acc[k] += __shfl_xor(acc[k], 2);
  }
  float* ep = em + (size_t)n * Kn + 3 * q;
#pragma unroll
  for (int j = 0; j < 3; ++j) ep[j] = acc[3 * q + j] + bo[3 * q + j];
}

// ---------------- K4: Viterbi (pipelined em prefetch) --------------------
#define AMAX(v, a, v2, a2) { if ((v2) > (v)) { (v) = (v2); (a) = (a2); } }

__global__ __launch_bounds__(64) void viterbi_kernel(
    const float* __restrict__ em, const float* __restrict__ trans,
    float* __restrict__ out) {
  __shared__ __align__(16) float em_s[Tn * Kn];
  __shared__ float trans_s[Kn * Kn];
  __shared__ unsigned char bp[(Tn - 1) * Kn];
  __shared__ short path_s[Tn];
  const int tid = threadIdx.x;
  const int b = blockIdx.x;
  {
    const float4* ebv = (const float4*)(em + (size_t)b * Tn * Kn);
    float4* emv = (float4*)em_s;
    for (int i = tid; i < (Tn * Kn) / 4; i += 64) emv[i] = ebv[i];
  }
  for (int i = tid; i < Kn * Kn; i += 64) trans_s[i] = trans[i];
  __syncthreads();
  const int lane = (tid < Kn) ? tid : 0;
  float treg[Kn];
#pragma unroll
  for (int f = 0; f < Kn; ++f) treg[f] = trans_s[f * Kn + lane];
  float prev = em_s[lane];
  // software-pipelined em read: e_nx for step t prefetched at step t-1,
  // keeping the ~120cyc LDS latency off the serial DP chain.
  float e_nx = em_s[Kn + lane];
  for (int t = 1; t < Tn; ++t) {
    float cv[Kn];
#pragma unroll
    for (int f = 0; f < Kn; ++f) cv[f] = __shfl(prev, f) + treg[f];
    const float e_use = e_nx;
    if (t + 1 < Tn) e_nx = em_s[(t + 1) * Kn + lane];  // off-chain prefetch
    float m0 = cv[0], m1 = cv[2], m2 = cv[4], m3 = cv[6], m4 = cv[8], m5 = cv[10];
    int a0 = 0, a1 = 2, a2 = 4, a3 = 6, a4 = 8, a5 = 10;
    AMAX(m0, a0, cv[1], 1);  AMAX(m1, a1, cv[3], 3);
    AMAX(m2, a2, cv[5], 5);  AMAX(m3, a3, cv[7], 7);
    AMAX(m4, a4, cv[9], 9);  AMAX(m5, a5, cv[11], 11);
    AMAX(m0, a0, m1, a1); AMAX(m2, a2, m3, a3); AMAX(m4, a4, m5, a5);
    AMAX(m0, a0, m2, a2); AMAX(m0, a0, m4, a4);
    prev = e_use + m0;
    if (tid < Kn) bp[(t - 1) * Kn + tid] = (unsigned char)a0;
  }
  float fv[Kn];
#pragma unroll
  for (int f = 0; f < Kn; ++f) fv[f] = __shfl(prev, f);
  float m0 = fv[0], m1 = fv[2], m2 = fv[4], m3 = fv[6], m4 = fv[8], m5 = fv[10];
  int a0 = 0, a1 = 2, a2 = 4, a3 = 6, a4 = 8, a5 = 10;
  AMAX(m0, a0, fv[1], 1);  AMAX(m1, a1, fv[3], 3);
  AMAX(m2, a2, fv[5], 5);  AMAX(m3, a3, fv[7], 7);
  AMAX(m4, a4, fv[9], 9);  AMAX(m5, a5, fv[11], 11);
  AMAX(m0, a0, m1, a1); AMAX(m2, a2, m3, a3); AMAX(m4, a4, m5, a5);
  AMAX(m0, a0, m2, a2); AMAX(m0, a0, m4, a4);
  __syncthreads();
  if (tid == 0) {
    out[b] = m0;
    int cur = a0;
    for (int i = Tn - 2; i >= 0; --i) {
      path_s[i + 1] = (short)cur;
      cur = bp[i * Kn + cur];
    }
    path_s[0] = (short)cur;
  }
  __syncthreads();
  for (int i = tid; i < Tn; i += 64)
    out[Bn + (size_t)b * Tn + i] = (float)path_s[i];
}

extern "C" void kernel_launch(void* const* d_in, const int* in_sizes, int n_in,
                              void* d_out, int out_size, void* d_ws, size_t ws_size,
                              hipStream_t stream) {
  const int*   sent  = (const int*)d_in[0];
  const float* embed = (const float*)d_in[1];
  const float* Wih_f = (const float*)d_in[2];
  const float* Whh_f = (const float*)d_in[3];
  const float* bih_f = (const float*)d_in[4];
  const float* bhh_f = (const float*)d_in[5];
  const float* Wih_b = (const float*)d_in[6];
  const float* Whh_b = (const float*)d_in[7];
  const float* bih_b = (const float*)d_in[8];
  const float* bhh_b = (const float*)d_in[9];
  const float* Wout  = (const float*)d_in[10];
  const float* bout  = (const float*)d_in[11];
  const float* trans = (const float*)d_in[12];
  const float* h0    = (const float*)d_in[13];
  const float* c0    = (const float*)d_in[14];
  float* out = (float*)d_out;

  char* ws = (char*)d_ws;
  const size_t xgBytes   = (size_t)Bn * Tn * G4 * sizeof(float);  // 64 MiB
  const size_t featBytes = (size_t)Bn * Tn * Hn * sizeof(float);  // 32 MiB
  const size_t emBytes   = (size_t)Bn * Tn * Kn * sizeof(float);  //  3 MiB
  const int tokBlocks = (Bn * Tn) / 64;  // 1024

  if (ws_size >= 2 * xgBytes + featBytes + emBytes) {
    float* xgF   = (float*)ws;
    float* xgB   = (float*)(ws + xgBytes);
    float* feats = (float*)(ws + 2 * xgBytes);
    float* emis  = (float*)(ws + 2 * xgBytes + featBytes);
    proj_kernel<<<dim3(tokBlocks, 2, 2), 256, 0, stream>>>(
        sent, embed, Wih_f, Wih_b, bih_f, bhh_f, bih_b, bhh_b, xgF, xgB, -1);
    lstm_kernel<<<256, 512, 0, stream>>>(xgF, xgB, Whh_f, Whh_b, h0, c0, feats, -1);
    emis_kernel<<<1024, 256, 0, stream>>>(feats, Wout, bout, emis);
    viterbi_kernel<<<128, 64, 0, stream>>>(emis, trans, out);
  } else {
    float* xgS   = (float*)ws;
    float* feats = (float*)(ws + xgBytes);
    float* emis  = (float*)(ws + xgBytes + featBytes);
    proj_kernel<<<dim3(tokBlocks, 2, 1), 256, 0, stream>>>(
        sent, embed, Wih_f, Wih_b, bih_f, bhh_f, bih_b, bhh_b, xgS, xgS, 0);
    lstm_kernel<<<128, 512, 0, stream>>>(xgS, xgS, Whh_f, Whh_f, h0, c0, feats, 0);
    proj_kernel<<<dim3(tokBlocks, 2, 1), 256, 0, stream>>>(
        sent, embed, Wih_f, Wih_b, bih_f, bhh_f, bih_b, bhh_b, xgS, xgS, 1);
    lstm_kernel<<<128, 512, 0, stream>>>(xgS, xgS, Whh_b, Whh_b, h0, c0, feats, 1);
    emis_kernel<<<1024, 256, 0, stream>>>(feats, Wout, bout, emis);
    viterbi_kernel<<<128, 64, 0, stream>>>(emis, trans, out);
  }
}